// Round 4
// baseline (3451.110 us; speedup 1.0000x reference)
//
#include <hip/hip_runtime.h>
#include <hip/hip_bf16.h>

#define BB 4096
#define TT 512
#define HH 256

typedef __bf16 bf16x8 __attribute__((ext_vector_type(8)));
typedef float f32x4 __attribute__((ext_vector_type(4)));

#define MFMA __builtin_amdgcn_mfma_f32_16x16x32_bf16

// Extended-K layout: K = 288 (256 h | x at k=256 | 1 at k=257 | zeros).
// 65 column-tiles (ctg 0..63 gates, 64 = heads: col0=mean,col1=logvar), 9 k-tiles.
// frag (ctg,kt): lane l, elem e = W_ext[ctg*16 + (l&15)][kt*32 + 8*(l>>4) + e]
// stored at wB[((ctg*9 + kt)*64 + l)*8 + e].
__global__ void prep_weights(const float* __restrict__ w_hh, const float* __restrict__ w_ih,
                             const float* __restrict__ b_ih, const float* __restrict__ b_hh,
                             const float* __restrict__ w_mean, const float* __restrict__ b_mean,
                             const float* __restrict__ w_logvar, const float* __restrict__ b_logvar,
                             __bf16* __restrict__ wB) {
    int idx = blockIdx.x * blockDim.x + threadIdx.x;
    if (idx >= 65 * 9 * 64) return;
    int l = idx & 63;
    int kt = (idx >> 6) % 9;
    int ctg = idx / (9 * 64);
    int col = l & 15;
    int k0 = kt * 32 + 8 * (l >> 4);
    bf16x8 v;
#pragma unroll
    for (int e = 0; e < 8; ++e) {
        int k = k0 + e;
        float f = 0.f;
        if (ctg < 64) {
            int n = ctg * 16 + col;
            if (k < 256) f = w_hh[n * HH + k];
            else if (k == 256) f = w_ih[n];
            else if (k == 257) f = b_ih[n] + b_hh[n];
        } else if (col == 0) {
            if (k < 256) f = w_mean[k];
            else if (k == 257) f = b_mean[0];
        } else if (col == 1) {
            if (k < 256) f = w_logvar[k];
            else if (k == 257) f = b_logvar[0];
        }
        v[e] = (__bf16)f;
    }
    *(bf16x8*)(wB + (size_t)idx * 8) = v;
}

__device__ __forceinline__ float sigmoid_f(float v) { return 1.f / (1.f + __expf(-v)); }
// NaN-safe tanh: 1 - 2/(exp(2v)+1)
__device__ __forceinline__ float tanh_f(float v) { float e = __expf(2.f * v); return 1.f - 2.f / (e + 1.f); }

__global__ __launch_bounds__(1024, 4) void lstm_fused(
    const float* __restrict__ x, const float* __restrict__ eps,
    const __bf16* __restrict__ wB, float* __restrict__ out)
{
    __shared__ __align__(16) __bf16 wlds[16][8][512];   // 131072 B: kt 3,4 per cc
    __shared__ __align__(16) __bf16 hbuf[2][16][296];   // 18944 B, ping-pong, K=288 + pad
    __shared__ __align__(16) __bf16 headw[9][512];      // 9216 B
    __shared__ float obuf[3][16][16];                   // 3072 B
    // total 162304 B

    const int tid = threadIdx.x;
    const int w = tid >> 6;          // wave 0..15
    const int l = tid & 63;
    const int m0 = blockIdx.x * 16;

    for (int i = tid; i < 2 * 16 * 296; i += 1024) (&hbuf[0][0][0])[i] = (__bf16)0.f;
    for (int i = tid; i < 9 * 64; i += 1024) {
        int kt = i >> 6, hl = i & 63;
        *(bf16x8*)&headw[kt][hl * 8] = *(const bf16x8*)(wB + (size_t)((64 * 9 + kt) * 64 + hl) * 8);
    }

    // wave w owns ctg = w + 16*cc (cc = gate index); REG kt {0,1,2,8}, LDS kt {3,4}
    bf16x8 wreg[16];
#pragma unroll
    for (int cc = 0; cc < 4; ++cc) {
        const int ctg = w + 16 * cc;
        const size_t fb = (size_t)(ctg * 9) * 64;
        wreg[cc * 4 + 0] = *(const bf16x8*)(wB + (fb + 0 * 64 + l) * 8);
        wreg[cc * 4 + 1] = *(const bf16x8*)(wB + (fb + 1 * 64 + l) * 8);
        wreg[cc * 4 + 2] = *(const bf16x8*)(wB + (fb + 2 * 64 + l) * 8);
        wreg[cc * 4 + 3] = *(const bf16x8*)(wB + (fb + 8 * 64 + l) * 8);
        *(bf16x8*)&wlds[w][cc * 2 + 0][l * 8] = *(const bf16x8*)(wB + (fb + 3 * 64 + l) * 8);
        *(bf16x8*)&wlds[w][cc * 2 + 1][l * 8] = *(const bf16x8*)(wB + (fb + 4 * 64 + l) * 8);
    }

    __syncthreads();
    if (tid < 16) {
        hbuf[0][tid][257] = (__bf16)1.0f;
        hbuf[1][tid][257] = (__bf16)1.0f;
        hbuf[1][tid][256] = (__bf16)x[(size_t)(m0 + tid) * TT];  // x_0 (rb of t=0 is buf 1)
    }

    const int arow = l & 15;
    const int ako = 8 * (l >> 4);
    const int r0 = (l >> 4) * 4;
    const bool headwave = (w == 0);
    float c[4] = {0.f, 0.f, 0.f, 0.f};

    // streamed kt 5,6,7: base anchored at kt=6 so offsets are +/-1024 B immediates
    const __bf16* scc0 = wB + ((size_t)((w +  0) * 9 + 6) * 64 + l) * 8;
    const __bf16* scc1 = wB + ((size_t)((w + 16) * 9 + 6) * 64 + l) * 8;
    const __bf16* scc2 = wB + ((size_t)((w + 32) * 9 + 6) * 64 + l) * 8;
    const __bf16* scc3 = wB + ((size_t)((w + 48) * 9 + 6) * 64 + l) * 8;

    __syncthreads();

    for (int t = 0; t < TT; ++t) {
        const int pb = t & 1, rb = pb ^ 1;
        const bool dh = headwave && (t >= 1);

        float xn = 0.f;
        if (tid < 16 && t + 1 < TT) xn = x[(size_t)(m0 + tid) * TT + (t + 1)];
        float ev[4] = {0.f, 0.f, 0.f, 0.f};
        if (dh && (l & 15) == 0) {
#pragma unroll
            for (int j = 0; j < 4; ++j) ev[j] = eps[(size_t)(m0 + r0 + j) * TT + (t - 1)];
        }
        // prefetch streamed kt=5 (consumed ~20 MFMAs later)
        bf16x8 sA0 = *(const bf16x8*)(scc0 - 512);
        bf16x8 sA1 = *(const bf16x8*)(scc1 - 512);
        bf16x8 sA2 = *(const bf16x8*)(scc2 - 512);
        bf16x8 sA3 = *(const bf16x8*)(scc3 - 512);

        f32x4 a0 = {0,0,0,0}, a1 = {0,0,0,0}, a2 = {0,0,0,0}, a3 = {0,0,0,0};
        f32x4 ah = {0,0,0,0};
        bf16x8 af;

        // kt 0..2 from wreg
        af = *(const bf16x8*)&hbuf[rb][arow][0 * 32 + ako];
        a0 = MFMA(af, wreg[0], a0,0,0,0);  a1 = MFMA(af, wreg[4], a1,0,0,0);
        a2 = MFMA(af, wreg[8], a2,0,0,0);  a3 = MFMA(af, wreg[12], a3,0,0,0);
        if (dh) ah = MFMA(af, *(const bf16x8*)&headw[0][l*8], ah,0,0,0);

        af = *(const bf16x8*)&hbuf[rb][arow][1 * 32 + ako];
        a0 = MFMA(af, wreg[1], a0,0,0,0);  a1 = MFMA(af, wreg[5], a1,0,0,0);
        a2 = MFMA(af, wreg[9], a2,0,0,0);  a3 = MFMA(af, wreg[13], a3,0,0,0);
        if (dh) ah = MFMA(af, *(const bf16x8*)&headw[1][l*8], ah,0,0,0);

        af = *(const bf16x8*)&hbuf[rb][arow][2 * 32 + ako];
        a0 = MFMA(af, wreg[2], a0,0,0,0);  a1 = MFMA(af, wreg[6], a1,0,0,0);
        a2 = MFMA(af, wreg[10], a2,0,0,0); a3 = MFMA(af, wreg[14], a3,0,0,0);
        if (dh) ah = MFMA(af, *(const bf16x8*)&headw[2][l*8], ah,0,0,0);

        // kt 3,4 from LDS
        af = *(const bf16x8*)&hbuf[rb][arow][3 * 32 + ako];
        a0 = MFMA(af, *(const bf16x8*)&wlds[w][0][l*8], a0,0,0,0);
        a1 = MFMA(af, *(const bf16x8*)&wlds[w][2][l*8], a1,0,0,0);
        a2 = MFMA(af, *(const bf16x8*)&wlds[w][4][l*8], a2,0,0,0);
        a3 = MFMA(af, *(const bf16x8*)&wlds[w][6][l*8], a3,0,0,0);
        if (dh) ah = MFMA(af, *(const bf16x8*)&headw[3][l*8], ah,0,0,0);

        af = *(const bf16x8*)&hbuf[rb][arow][4 * 32 + ako];
        a0 = MFMA(af, *(const bf16x8*)&wlds[w][1][l*8], a0,0,0,0);
        a1 = MFMA(af, *(const bf16x8*)&wlds[w][3][l*8], a1,0,0,0);
        a2 = MFMA(af, *(const bf16x8*)&wlds[w][5][l*8], a2,0,0,0);
        a3 = MFMA(af, *(const bf16x8*)&wlds[w][7][l*8], a3,0,0,0);
        if (dh) ah = MFMA(af, *(const bf16x8*)&headw[4][l*8], ah,0,0,0);

        // kt 5 (streamed, prefetched) -> reissue kt 6
        af = *(const bf16x8*)&hbuf[rb][arow][5 * 32 + ako];
        a0 = MFMA(af, sA0, a0,0,0,0);  a1 = MFMA(af, sA1, a1,0,0,0);
        a2 = MFMA(af, sA2, a2,0,0,0);  a3 = MFMA(af, sA3, a3,0,0,0);
        if (dh) ah = MFMA(af, *(const bf16x8*)&headw[5][l*8], ah,0,0,0);
        sA0 = *(const bf16x8*)(scc0);  sA1 = *(const bf16x8*)(scc1);
        sA2 = *(const bf16x8*)(scc2);  sA3 = *(const bf16x8*)(scc3);

        // kt 6 -> reissue kt 7
        af = *(const bf16x8*)&hbuf[rb][arow][6 * 32 + ako];
        a0 = MFMA(af, sA0, a0,0,0,0);  a1 = MFMA(af, sA1, a1,0,0,0);
        a2 = MFMA(af, sA2, a2,0,0,0);  a3 = MFMA(af, sA3, a3,0,0,0);
        if (dh) ah = MFMA(af, *(const bf16x8*)&headw[6][l*8], ah,0,0,0);
        sA0 = *(const bf16x8*)(scc0 + 512);  sA1 = *(const bf16x8*)(scc1 + 512);
        sA2 = *(const bf16x8*)(scc2 + 512);  sA3 = *(const bf16x8*)(scc3 + 512);

        // kt 7
        af = *(const bf16x8*)&hbuf[rb][arow][7 * 32 + ako];
        a0 = MFMA(af, sA0, a0,0,0,0);  a1 = MFMA(af, sA1, a1,0,0,0);
        a2 = MFMA(af, sA2, a2,0,0,0);  a3 = MFMA(af, sA3, a3,0,0,0);
        if (dh) ah = MFMA(af, *(const bf16x8*)&headw[7][l*8], ah,0,0,0);

        // kt 8 (x + bias fold) from wreg
        af = *(const bf16x8*)&hbuf[rb][arow][8 * 32 + ako];
        a0 = MFMA(af, wreg[3], a0,0,0,0);  a1 = MFMA(af, wreg[7], a1,0,0,0);
        a2 = MFMA(af, wreg[11], a2,0,0,0); a3 = MFMA(af, wreg[15], a3,0,0,0);
        if (dh) ah = MFMA(af, *(const bf16x8*)&headw[8][l*8], ah,0,0,0);

        // ---- heads epilogue for h_{t-1} (wave 0): biases already folded ----
        if (dh) {
            const int slot = (t - 1) & 15;
#pragma unroll
            for (int j = 0; j < 4; ++j) {
                float lvn = __shfl(ah[j], (l & 48) | 1);  // col-1 lane = logvar
                if ((l & 15) == 0) {
                    float lv = fminf(fmaxf(lvn, -10.f), 2.f);
                    obuf[0][r0 + j][slot] = ah[j] + __expf(0.5f * lv) * ev[j];
                    obuf[1][r0 + j][slot] = ah[j];
                    obuf[2][r0 + j][slot] = lv;
                }
            }
        }

        // ---- elementwise LSTM cell: gates i,f,g,o = a0..a3, unit u, rows r0+j ----
        {
            const int u = 16 * w + arow;
#pragma unroll
            for (int j = 0; j < 4; ++j) {
                float ia = sigmoid_f(a0[j]);
                float fa = sigmoid_f(a1[j]);
                float ga = tanh_f(a2[j]);
                float oa = sigmoid_f(a3[j]);
                float cn = fa * c[j] + ia * ga;
                c[j] = cn;
                hbuf[pb][r0 + j][u] = (__bf16)(oa * tanh_f(cn));
            }
        }
        if (tid < 16 && t + 1 < TT) hbuf[pb][tid][256] = (__bf16)xn;  // x_{t+1}

        // ---- coalesced output flush every 16 steps ----
        if ((t & 15) == 0 && t > 0) {
            __syncthreads();
            if (tid < 192) {
                const int o = tid >> 6, rr = (tid >> 2) & 15, q = tid & 3;
                f32x4 v = *(const f32x4*)&obuf[o][rr][q * 4];
                *(f32x4*)(out + (size_t)o * BB * TT + (size_t)(m0 + rr) * TT + (t - 16) + q * 4) = v;
            }
        }
        __syncthreads();
    }

    // ---- tail: head for t = TT-1 (h in hbuf[1]) + final flush ----
    {
        if (headwave) {
            f32x4 ah = {0,0,0,0};
            float ev[4] = {0.f, 0.f, 0.f, 0.f};
            if ((l & 15) == 0) {
#pragma unroll
                for (int j = 0; j < 4; ++j) ev[j] = eps[(size_t)(m0 + r0 + j) * TT + (TT - 1)];
            }
#pragma unroll
            for (int kt = 0; kt < 9; ++kt) {
                bf16x8 af = *(const bf16x8*)&hbuf[1][arow][kt * 32 + ako];
                ah = MFMA(af, *(const bf16x8*)&headw[kt][l * 8], ah, 0, 0, 0);
            }
#pragma unroll
            for (int j = 0; j < 4; ++j) {
                float lvn = __shfl(ah[j], (l & 48) | 1);
                if ((l & 15) == 0) {
                    float lv = fminf(fmaxf(lvn, -10.f), 2.f);
                    obuf[0][r0 + j][15] = ah[j] + __expf(0.5f * lv) * ev[j];
                    obuf[1][r0 + j][15] = ah[j];
                    obuf[2][r0 + j][15] = lv;
                }
            }
        }
        __syncthreads();
        if (tid < 192) {
            const int o = tid >> 6, rr = (tid >> 2) & 15, q = tid & 3;
            f32x4 v = *(const f32x4*)&obuf[o][rr][q * 4];
            *(f32x4*)(out + (size_t)o * BB * TT + (size_t)(m0 + rr) * TT + (TT - 16) + q * 4) = v;
        }
    }
}

extern "C" void kernel_launch(void* const* d_in, const int* in_sizes, int n_in,
                              void* d_out, int out_size, void* d_ws, size_t ws_size,
                              hipStream_t stream) {
    const float* x = (const float*)d_in[0];
    const float* eps = (const float*)d_in[1];
    const float* w_ih = (const float*)d_in[2];
    const float* w_hh = (const float*)d_in[3];
    const float* b_ih = (const float*)d_in[4];
    const float* b_hh = (const float*)d_in[5];
    const float* w_mean = (const float*)d_in[6];
    const float* b_mean = (const float*)d_in[7];
    const float* w_logvar = (const float*)d_in[8];
    const float* b_logvar = (const float*)d_in[9];

    __bf16* wB = (__bf16*)d_ws;  // 585 KB extended fragment-ordered bf16 weights

    prep_weights<<<(65 * 9 * 64 + 255) / 256, 256, 0, stream>>>(
        w_hh, w_ih, b_ih, b_hh, w_mean, b_mean, w_logvar, b_logvar, wB);
    lstm_fused<<<256, 1024, 0, stream>>>(x, eps, wB, (float*)d_out);
}